// Round 1
// baseline (1340.654 us; speedup 1.0000x reference)
//
#include <hip/hip_runtime.h>

// ReadGate: q = (emb[query] @ qW.T + qb); sims = <q, memory[b,m,:]>/8;
// w = softmax_m(sims); pooled = sum_m w*memory[b,m,:]; out = pooled @ oW.T + ob
// B = M = 2048, D = V = 64. All f32 except query (int32).
//
// Memory-bound: memory tensor is 1.074 GB, everything else is KB.
// Strategy: single fused pass (online softmax) so memory is read from HBM
// exactly once. One block per batch row b; 4 waves per block, each wave keeps
// an independent online-softmax state (max, denom, acc[64]) over its quarter
// of the m-range; states merged associatively at the end.
//
// Lane layout inside a wave (per iteration, 16 consecutive m rows per block):
//   mq = lane>>4 (which of 4 m-rows), cq = lane&15 (which float4 of the 64-d row)
//   -> one global_load_dwordx4 per lane = contiguous 1 KB per wave. Perfect
//      coalescing; dot reduced with 4 shfl_xor (1,2,4,8) within 16-lane groups.

static constexpr int D = 64;
static constexpr int M = 2048;
// fold 1/sqrt(64) and log2(e) into q so softmax uses native v_exp_f32 (2^x)
static constexpr float SCALE = 0.125f * 1.44269504088896340736f;

__global__ __launch_bounds__(256, 8)
void readgate_kernel(const int* __restrict__ query,
                     const float* __restrict__ memory,
                     const float* __restrict__ emb,
                     const float* __restrict__ qW,
                     const float* __restrict__ qb,
                     const float* __restrict__ oW,
                     const float* __restrict__ ob,
                     float* __restrict__ out)
{
    __shared__ float s_oW[D * D];     // 16 KB, staged once per block
    __shared__ float s_q[D];
    __shared__ float s_wacc[4][D];
    __shared__ float s_wmx[4];
    __shared__ float s_wl[4];
    __shared__ float s_pooled[D];

    const int tid  = threadIdx.x;
    const int lane = tid & 63;
    const int w    = tid >> 6;       // wave id 0..3
    const int b    = blockIdx.x;

    // ---- stage oW into LDS (coalesced float4); it's reused by the epilogue
    {
        const float4* s = (const float4*)oW;
        float4*       d = (float4*)s_oW;
        d[tid]       = s[tid];
        d[tid + 256] = s[tid + 256];
        d[tid + 512] = s[tid + 512];
        d[tid + 768] = s[tid + 768];
    }

    // ---- q = emb[query[b]] @ qW.T + qb, scaled; tiny (64x64), wave 0 only.
    if (tid < D) {
        const int qi = query[b];
        const float* e  = emb + qi * D;     // broadcast reads (L1)
        const float* wr = qW + tid * D;     // 16 KB, L2-resident after block 0
        float a = qb[tid];
        #pragma unroll 8
        for (int k = 0; k < D; ++k) a = fmaf(e[k], wr[k], a);
        s_q[tid] = a * SCALE;
    }
    __syncthreads();

    const int cq = lane & 15;   // column quad (d = cq*4 .. cq*4+3)
    const int mq = lane >> 4;   // m sub-row within the wave's 4
    const float4 qf = ((const float4*)s_q)[cq];

    const float4* src = (const float4*)(memory + (size_t)b * M * D)
                      + (size_t)((w * 4 + mq) * 16 + cq);
    // per iteration the block consumes 16 m rows = 256 float4

    float  mx  = -1e30f;
    float  l   = 0.0f;
    float4 acc = make_float4(0.f, 0.f, 0.f, 0.f);

    float4 v = src[0];
    #pragma unroll 2
    for (int it = 0; it < 128; ++it) {
        // prefetch next chunk (clamped; last re-reads an L1-hot line)
        const int nxt = (it + 1 < 128) ? (it + 1) : 127;
        float4 vn = src[(size_t)nxt * 256];

        // partial dot over this lane's 4 columns
        float s = v.x * qf.x + v.y * qf.y + v.z * qf.z + v.w * qf.w;
        // reduce across the 16 lanes sharing mq -> full 64-d dot (replicated)
        s += __shfl_xor(s, 1);
        s += __shfl_xor(s, 2);
        s += __shfl_xor(s, 4);
        s += __shfl_xor(s, 8);

        // wave-wide max over the 4 new logits (uniform across wave)
        float sm = fmaxf(s, __shfl_xor(s, 16));
        sm = fmaxf(sm, __shfl_xor(sm, 32));

        const float nmx   = fmaxf(mx, sm);
        const float alpha = __builtin_amdgcn_exp2f(mx - nmx); // rescale old state
        const float p     = __builtin_amdgcn_exp2f(s - nmx);  // weight of this m

        // sum of the 4 distinct p's (uniform across wave)
        float ps = p + __shfl_xor(p, 16);
        ps += __shfl_xor(ps, 32);

        l  = fmaf(l, alpha, ps);
        mx = nmx;

        acc.x = fmaf(acc.x, alpha, p * v.x);
        acc.y = fmaf(acc.y, alpha, p * v.y);
        acc.z = fmaf(acc.z, alpha, p * v.z);
        acc.w = fmaf(acc.w, alpha, p * v.w);

        v = vn;
    }

    // reduce acc over the 4 mq groups (same running mx/l across the wave)
    acc.x += __shfl_xor(acc.x, 16);  acc.x += __shfl_xor(acc.x, 32);
    acc.y += __shfl_xor(acc.y, 16);  acc.y += __shfl_xor(acc.y, 32);
    acc.z += __shfl_xor(acc.z, 16);  acc.z += __shfl_xor(acc.z, 32);
    acc.w += __shfl_xor(acc.w, 16);  acc.w += __shfl_xor(acc.w, 32);

    if (lane < 16) ((float4*)s_wacc[w])[lane] = acc;   // lanes 0..15 have cq=lane
    if (lane == 0) { s_wmx[w] = mx; s_wl[w] = l; }
    __syncthreads();

    // ---- merge the 4 per-wave online-softmax states; normalize pooled
    if (tid < D) {
        const float M0 = fmaxf(fmaxf(s_wmx[0], s_wmx[1]),
                               fmaxf(s_wmx[2], s_wmx[3]));
        float L = 0.f, pd = 0.f;
        #pragma unroll
        for (int j = 0; j < 4; ++j) {
            const float sc = __builtin_amdgcn_exp2f(s_wmx[j] - M0);
            L  = fmaf(s_wl[j], sc, L);
            pd = fmaf(s_wacc[j][tid], sc, pd);
        }
        s_pooled[tid] = pd / L;
    }
    __syncthreads();

    // ---- out[b, v] = <pooled, oW[v,:]> + ob[v]
    if (tid < D) {
        float o = ob[tid];
        const float* wr = s_oW + tid * D;
        // rotated index: bank = (tid+k)%32 -> conflict-free (2-way is free)
        #pragma unroll 8
        for (int k = 0; k < D; ++k) {
            const int d = (tid + k) & 63;
            o = fmaf(s_pooled[d], wr[d], o);
        }
        out[b * D + tid] = o;
    }
}

extern "C" void kernel_launch(void* const* d_in, const int* in_sizes, int n_in,
                              void* d_out, int out_size, void* d_ws, size_t ws_size,
                              hipStream_t stream) {
    const int*   query  = (const int*)  d_in[0];
    const float* memory = (const float*)d_in[1];
    const float* emb    = (const float*)d_in[2];
    const float* qW     = (const float*)d_in[3];
    const float* qb     = (const float*)d_in[4];
    const float* oW     = (const float*)d_in[5];
    const float* ob     = (const float*)d_in[6];
    float* out = (float*)d_out;

    readgate_kernel<<<dim3(2048), dim3(256), 0, stream>>>(
        query, memory, emb, qW, qb, oW, ob, out);
}